// Round 2
// baseline (443.464 us; speedup 1.0000x reference)
//
#include <hip/hip_runtime.h>
#include <hip/hip_bf16.h>

#define H 4
#define NS 8192
#define NT 4096
#define DIN 128
#define DOUT 64
#define ROW_CAP 1024
#define COL_CAP 512
#define NEGBIG -3.0e38f

__device__ __forceinline__ float lrelu(float x) { return x >= 0.f ? x : 0.1f * x; }
__device__ __forceinline__ float eluf(float x) { return x > 0.f ? x : expm1f(x); }

__device__ __forceinline__ float waveMax(float v) {
    for (int off = 32; off > 0; off >>= 1) v = fmaxf(v, __shfl_xor(v, off, 64));
    return v;
}
__device__ __forceinline__ float waveSum(float v) {
    for (int off = 32; off > 0; off >>= 1) v += __shfl_xor(v, off, 64);
    return v;
}

// ---------------------------------------------------------------------------
// Projection: Hout[h,s,o] = sum_i X[s,i] * W[h,i,o];  b[h,s] = Hout[h,s,:]·a[h,:]
// grid (N/16, H), block 256. Thread: row r = tid>>4 (16 rows), feats fg..fg+3.
// ---------------------------------------------------------------------------
__global__ __launch_bounds__(256) void proj_kernel(
    const float* __restrict__ X, const float* __restrict__ W,
    const float* __restrict__ a_vec, float* __restrict__ Hout,
    float* __restrict__ b_out, int N) {
    __shared__ float w_lds[DIN * DOUT];   // 32 KB
    __shared__ float a_lds[16 * 129];     // padded: +1 word avoids bank conflict
    const int h = blockIdx.y;
    const int row0 = blockIdx.x * 16;
    const int tid = threadIdx.x;

    const float* Wh = W + (size_t)h * DIN * DOUT;
    for (int i = tid; i < DIN * DOUT; i += 256) w_lds[i] = Wh[i];
    for (int i = tid; i < 16 * DIN; i += 256) {
        int r = i >> 7, c = i & 127;
        a_lds[r * 129 + c] = X[(size_t)(row0 + r) * DIN + c];
    }
    __syncthreads();

    const int fg = (tid & 15) * 4;
    const int r = tid >> 4;
    const float* ar = &a_lds[r * 129];
    float acc0 = 0.f, acc1 = 0.f, acc2 = 0.f, acc3 = 0.f;
#pragma unroll 8
    for (int i = 0; i < DIN; ++i) {
        float av = ar[i];
        float4 wv = *reinterpret_cast<const float4*>(&w_lds[i * DOUT + fg]);
        acc0 += av * wv.x; acc1 += av * wv.y; acc2 += av * wv.z; acc3 += av * wv.w;
    }
    const int s = row0 + r;
    float4 o = make_float4(acc0, acc1, acc2, acc3);
    *reinterpret_cast<float4*>(&Hout[((size_t)h * N + s) * DOUT + fg]) = o;

    const float* av = a_vec + h * DOUT + fg;
    float part = acc0 * av[0] + acc1 * av[1] + acc2 * av[2] + acc3 * av[3];
    for (int off = 8; off > 0; off >>= 1) part += __shfl_xor(part, off, 64);
    if ((tid & 15) == 0) b_out[(size_t)h * N + s] = part;
}

// ---------------------------------------------------------------------------
// Mask build: one pass over dense A -> row-major + col-major bitmasks.
// grid (NS/64, NT/64), block 256. Each block: 64x64 tile. HBM-bound (134 MB).
// ---------------------------------------------------------------------------
__global__ __launch_bounds__(256) void mask_kernel(
    const float* __restrict__ A,
    unsigned long long* __restrict__ mask_row,
    unsigned long long* __restrict__ mask_col) {
    __shared__ unsigned long long rowbits[64];
    const int s0 = blockIdx.x * 64;
    const int t0 = blockIdx.y * 64;
    const int lane = threadIdx.x & 63;
    const int w = threadIdx.x >> 6;
    for (int rr = w; rr < 64; rr += 4) {
        const int t = t0 + rr;
        float v = A[(size_t)t * NS + s0 + lane];
        unsigned long long word = __ballot(v != 0.0f);
        if (lane == 0) {
            mask_row[(size_t)t * (NS / 64) + (s0 >> 6)] = word;
            rowbits[rr] = word;
        }
    }
    __syncthreads();
    if (threadIdx.x < 64) {
        const int j = threadIdx.x;
        unsigned long long cw = 0;
        for (int rr = 0; rr < 64; ++rr) cw |= ((rowbits[rr] >> j) & 1ull) << rr;
        mask_col[(size_t)(s0 + j) * (NT / 64) + (t0 >> 6)] = cw;
    }
}

// ---------------------------------------------------------------------------
// Row direction: softmax over sources s for each (h,t); h_ts = elu(attn @ hs).
// grid NT, block 256 (wave = head). out_ts[t, h*64+f].
// ---------------------------------------------------------------------------
__global__ __launch_bounds__(256) void attn_row_kernel(
    const unsigned long long* __restrict__ mask_row,
    const float* __restrict__ bs, const float* __restrict__ bt,
    const float* __restrict__ hs, float* __restrict__ out_ts) {
    __shared__ unsigned short list[ROW_CAP];
    __shared__ float wbuf[H][ROW_CAP];   // 16 KB
    __shared__ float sums[H];
    __shared__ int cnts[NS / 64 + 1];

    const int t = blockIdx.x;
    const int tid = threadIdx.x;
    const int NW = NS / 64;  // 128 words

    unsigned long long word = 0;
    if (tid < NW) {
        word = mask_row[(size_t)t * NW + tid];
        cnts[tid] = __popcll(word);
    }
    __syncthreads();
    if (tid == 0) {
        int run = 0;
        for (int i = 0; i < NW; ++i) { int c = cnts[i]; cnts[i] = run; run += c; }
        cnts[NW] = run;
    }
    __syncthreads();
    int nnz = cnts[NW];
    if (tid < NW) {
        int off = cnts[tid];
        unsigned long long wd = word;
        const int base = tid * 64;
        while (wd) {
            int b = __ffsll((long long)wd) - 1;
            if (off < ROW_CAP) list[off] = (unsigned short)(base + b);
            ++off;
            wd &= wd - 1;
        }
    }
    if (nnz > ROW_CAP) nnz = ROW_CAP;  // statistically unreachable guard
    __syncthreads();

    const int h = tid >> 6, lane = tid & 63;
    const float btv = bt[(size_t)h * NT + t];
    float m = NEGBIG;
    for (int j = lane; j < nnz; j += 64) {
        float p = bs[(size_t)h * NS + list[j]];
        wbuf[h][j] = p;
        m = fmaxf(m, p);
    }
    m = waveMax(m);
    const float mrow = lrelu(btv + m);   // lrelu monotone => exact row max
    float ssum = 0.f;
    for (int j = lane; j < nnz; j += 64) {
        float wv = expf(lrelu(btv + wbuf[h][j]) - mrow);
        wbuf[h][j] = wv;
        ssum += wv;
    }
    ssum = waveSum(ssum);
    if (lane == 0) sums[h] = ssum;
    __syncthreads();

    float rs = sums[h];
    rs = rs > 0.f ? 1.0f / rs : 0.f;
    const float* hsh = hs + (size_t)h * NS * DOUT + lane;  // lane = feature
    // 4-way unrolled: independent accumulators expose MLP on the gathers.
    float a0 = 0.f, a1 = 0.f, a2 = 0.f, a3 = 0.f;
    int j = 0;
    for (; j + 3 < nnz; j += 4) {
        int i0 = list[j], i1 = list[j + 1], i2 = list[j + 2], i3 = list[j + 3];
        float w0 = wbuf[h][j], w1 = wbuf[h][j + 1], w2 = wbuf[h][j + 2], w3 = wbuf[h][j + 3];
        a0 += w0 * hsh[(size_t)i0 * DOUT];
        a1 += w1 * hsh[(size_t)i1 * DOUT];
        a2 += w2 * hsh[(size_t)i2 * DOUT];
        a3 += w3 * hsh[(size_t)i3 * DOUT];
    }
    for (; j < nnz; ++j) a0 += wbuf[h][j] * hsh[(size_t)list[j] * DOUT];
    float acc = (a0 + a1) + (a2 + a3);
    out_ts[(size_t)t * (H * DOUT) + h * DOUT + lane] = eluf(acc * rs);
}

// ---------------------------------------------------------------------------
// Col direction: softmax over targets t for each (h,s); h_st = elu(attn^T @ ht).
// grid NS, block 256 (wave = head). out_st[s, h*64+f].
// ---------------------------------------------------------------------------
__global__ __launch_bounds__(256) void attn_col_kernel(
    const unsigned long long* __restrict__ mask_col,
    const float* __restrict__ bs, const float* __restrict__ bt,
    const float* __restrict__ ht, float* __restrict__ out_st) {
    __shared__ unsigned short list[COL_CAP];
    __shared__ float wbuf[H][COL_CAP];   // 8 KB
    __shared__ float sums[H];
    __shared__ int cnts[NT / 64 + 1];

    const int s = blockIdx.x;
    const int tid = threadIdx.x;
    const int NW = NT / 64;  // 64 words

    unsigned long long word = 0;
    if (tid < NW) {
        word = mask_col[(size_t)s * NW + tid];
        cnts[tid] = __popcll(word);
    }
    __syncthreads();
    if (tid == 0) {
        int run = 0;
        for (int i = 0; i < NW; ++i) { int c = cnts[i]; cnts[i] = run; run += c; }
        cnts[NW] = run;
    }
    __syncthreads();
    int nnz = cnts[NW];
    if (tid < NW) {
        int off = cnts[tid];
        unsigned long long wd = word;
        const int base = tid * 64;
        while (wd) {
            int b = __ffsll((long long)wd) - 1;
            if (off < COL_CAP) list[off] = (unsigned short)(base + b);
            ++off;
            wd &= wd - 1;
        }
    }
    if (nnz > COL_CAP) nnz = COL_CAP;
    __syncthreads();

    const int h = tid >> 6, lane = tid & 63;
    const float bsv = bs[(size_t)h * NS + s];
    float m = NEGBIG;
    for (int j = lane; j < nnz; j += 64) {
        float p = bt[(size_t)h * NT + list[j]];
        wbuf[h][j] = p;
        m = fmaxf(m, p);
    }
    m = waveMax(m);
    const float mcol = lrelu(bsv + m);
    float ssum = 0.f;
    for (int j = lane; j < nnz; j += 64) {
        float wv = expf(lrelu(bsv + wbuf[h][j]) - mcol);
        wbuf[h][j] = wv;
        ssum += wv;
    }
    ssum = waveSum(ssum);
    if (lane == 0) sums[h] = ssum;
    __syncthreads();

    float rs = sums[h];
    rs = rs > 0.f ? 1.0f / rs : 0.f;
    const float* hth = ht + (size_t)h * NT * DOUT + lane;
    float a0 = 0.f, a1 = 0.f, a2 = 0.f, a3 = 0.f;
    int j = 0;
    for (; j + 3 < nnz; j += 4) {
        int i0 = list[j], i1 = list[j + 1], i2 = list[j + 2], i3 = list[j + 3];
        float w0 = wbuf[h][j], w1 = wbuf[h][j + 1], w2 = wbuf[h][j + 2], w3 = wbuf[h][j + 3];
        a0 += w0 * hth[(size_t)i0 * DOUT];
        a1 += w1 * hth[(size_t)i1 * DOUT];
        a2 += w2 * hth[(size_t)i2 * DOUT];
        a3 += w3 * hth[(size_t)i3 * DOUT];
    }
    for (; j < nnz; ++j) a0 += wbuf[h][j] * hth[(size_t)list[j] * DOUT];
    float acc = (a0 + a1) + (a2 + a3);
    out_st[(size_t)s * (H * DOUT) + h * DOUT + lane] = eluf(acc * rs);
}

// ---------------------------------------------------------------------------
extern "C" void kernel_launch(void* const* d_in, const int* in_sizes, int n_in,
                              void* d_out, int out_size, void* d_ws, size_t ws_size,
                              hipStream_t stream) {
    const float* input1 = (const float*)d_in[0];  // [8192,128]
    const float* input2 = (const float*)d_in[1];  // [4096,128]
    const float* A      = (const float*)d_in[2];  // [4096,8192]
    const float* Ws     = (const float*)d_in[3];  // [4,128,64]
    const float* Wt     = (const float*)d_in[4];  // [4,128,64]
    const float* a_src  = (const float*)d_in[5];  // [4,64]
    const float* a_tgt  = (const float*)d_in[6];  // [4,64]
    float* out = (float*)d_out;  // out_st [8192,256] then out_ts [4096,256]

    char* ws = (char*)d_ws;
    float* hs = (float*)(ws + 0);                              // 8 MB   [H,NS,64]
    float* ht = (float*)(ws + 8388608);                        // 4 MB   [H,NT,64]
    float* bs = (float*)(ws + 12582912);                       // 128 KB [H,NS]
    float* bt = (float*)(ws + 12713984);                       // 64 KB  [H,NT]
    unsigned long long* mask_row = (unsigned long long*)(ws + 12779520);  // 4 MB [NT][NS/64]
    unsigned long long* mask_col = (unsigned long long*)(ws + 16973824);  // 4 MB [NS][NT/64]

    proj_kernel<<<dim3(NS / 16, H), 256, 0, stream>>>(input1, Ws, a_src, hs, bs, NS);
    proj_kernel<<<dim3(NT / 16, H), 256, 0, stream>>>(input2, Wt, a_tgt, ht, bt, NT);
    mask_kernel<<<dim3(NS / 64, NT / 64), 256, 0, stream>>>(A, mask_row, mask_col);
    attn_row_kernel<<<NT, 256, 0, stream>>>(mask_row, bs, bt, hs,
                                            out + (size_t)NS * (H * DOUT));
    attn_col_kernel<<<NS, 256, 0, stream>>>(mask_col, bs, bt, ht, out);
}

// Round 5
// 428.990 us; speedup vs baseline: 1.0337x; 1.0337x over previous
//
#include <hip/hip_runtime.h>
#include <hip/hip_bf16.h>

#define H 4
#define NS 8192
#define NT 4096
#define DIN 128
#define DOUT 64
#define ROW_CAP 1024
#define COL_CAP 512
#define NEGBIG -3.0e38f

typedef unsigned short ushort8_t __attribute__((ext_vector_type(8)));

__device__ __forceinline__ float lrelu(float x) { return x >= 0.f ? x : 0.1f * x; }
__device__ __forceinline__ float eluf(float x) { return x > 0.f ? x : expm1f(x); }

__device__ __forceinline__ float waveMax(float v) {
    for (int off = 32; off > 0; off >>= 1) v = fmaxf(v, __shfl_xor(v, off, 64));
    return v;
}
__device__ __forceinline__ float waveSum(float v) {
    for (int off = 32; off > 0; off >>= 1) v += __shfl_xor(v, off, 64);
    return v;
}

// ---------------------------------------------------------------------------
// Projection: Hout[h,s,o] = sum_i X[s,i] * W[h,i,o];  b[h,s] = Hout[h,s,:]·a[h,:]
// grid (N/16, H), block 256.
// ---------------------------------------------------------------------------
__global__ __launch_bounds__(256) void proj_kernel(
    const float* __restrict__ X, const float* __restrict__ W,
    const float* __restrict__ a_vec, float* __restrict__ Hout,
    float* __restrict__ b_out, int N) {
    __shared__ float w_lds[DIN * DOUT];   // 32 KB
    __shared__ float a_lds[16 * 129];
    const int h = blockIdx.y;
    const int row0 = blockIdx.x * 16;
    const int tid = threadIdx.x;

    const float* Wh = W + (size_t)h * DIN * DOUT;
    for (int i = tid; i < DIN * DOUT; i += 256) w_lds[i] = Wh[i];
    for (int i = tid; i < 16 * DIN; i += 256) {
        int r = i >> 7, c = i & 127;
        a_lds[r * 129 + c] = X[(size_t)(row0 + r) * DIN + c];
    }
    __syncthreads();

    const int fg = (tid & 15) * 4;
    const int r = tid >> 4;
    const float* ar = &a_lds[r * 129];
    float acc0 = 0.f, acc1 = 0.f, acc2 = 0.f, acc3 = 0.f;
#pragma unroll 8
    for (int i = 0; i < DIN; ++i) {
        float av = ar[i];
        float4 wv = *reinterpret_cast<const float4*>(&w_lds[i * DOUT + fg]);
        acc0 += av * wv.x; acc1 += av * wv.y; acc2 += av * wv.z; acc3 += av * wv.w;
    }
    const int s = row0 + r;
    float4 o = make_float4(acc0, acc1, acc2, acc3);
    *reinterpret_cast<float4*>(&Hout[((size_t)h * N + s) * DOUT + fg]) = o;

    const float* av = a_vec + h * DOUT + fg;
    float part = acc0 * av[0] + acc1 * av[1] + acc2 * av[2] + acc3 * av[3];
    for (int off = 8; off > 0; off >>= 1) part += __shfl_xor(part, off, 64);
    if ((tid & 15) == 0) b_out[(size_t)h * N + s] = part;
}

// ---------------------------------------------------------------------------
// Mask build: one HBM pass over dense A -> row-major + col-major bitmasks.
// ---------------------------------------------------------------------------
__global__ __launch_bounds__(256) void mask_kernel(
    const float* __restrict__ A,
    unsigned long long* __restrict__ mask_row,
    unsigned long long* __restrict__ mask_col) {
    __shared__ unsigned long long rowbits[64];
    const int s0 = blockIdx.x * 64;
    const int t0 = blockIdx.y * 64;
    const int lane = threadIdx.x & 63;
    const int w = threadIdx.x >> 6;
    for (int rr = w; rr < 64; rr += 4) {
        const int t = t0 + rr;
        float v = A[(size_t)t * NS + s0 + lane];
        unsigned long long word = __ballot(v != 0.0f);
        if (lane == 0) {
            mask_row[(size_t)t * (NS / 64) + (s0 >> 6)] = word;
            rowbits[rr] = word;
        }
    }
    __syncthreads();
    if (threadIdx.x < 64) {
        const int j = threadIdx.x;
        unsigned long long cw = 0;
        for (int rr = 0; rr < 64; ++rr) cw |= ((rowbits[rr] >> j) & 1ull) << rr;
        mask_col[(size_t)(s0 + j) * (NT / 64) + (t0 >> 6)] = cw;
    }
}

// ---------------------------------------------------------------------------
// Shared machinery for the two attention kernels.
// Compaction: bitmask words -> index list via __shfl_up wave scan (no serial).
// Gather loop: 8-way unroll, b128 LDS reads (8 idx / 8 weights per 3 reads).
// ---------------------------------------------------------------------------
template <int NW, int CAP>
__device__ __forceinline__ int compact_list(
    const unsigned long long* __restrict__ mask, size_t mask_row_off,
    unsigned short* list, int* wtot, int tid) {
    unsigned long long word = 0;
    int c = 0;
    if (tid < NW) {
        word = mask[mask_row_off + tid];
        c = __popcll(word);
    }
    // inclusive wave scan
    int incl = c;
#pragma unroll
    for (int d = 1; d < 64; d <<= 1) {
        int v = __shfl_up(incl, d, 64);
        if ((tid & 63) >= d) incl += v;
    }
    if ((tid & 63) == 63) wtot[tid >> 6] = incl;
    __syncthreads();
    int base_off = 0;
#pragma unroll
    for (int wv = 0; wv < (NW / 64); ++wv) {
        int v = wtot[wv];
        if (wv < (tid >> 6)) base_off += v;
    }
    int nnz = 0;
#pragma unroll
    for (int wv = 0; wv < (NW / 64); ++wv) nnz += wtot[wv];
    if (tid < NW) {
        int off = base_off + incl - c;
        unsigned long long wd = word;
        const int base = tid * 64;
        while (wd) {
            int b = __ffsll((long long)wd) - 1;
            if (off < CAP) list[off] = (unsigned short)(base + b);
            ++off;
            wd &= wd - 1;
        }
    }
    return nnz > CAP ? CAP : nnz;
}

// Weighted gather: acc = sum_j w[j] * src[list[j]*DOUT + lane]
__device__ __forceinline__ float gather_accum(
    const unsigned short* __restrict__ list, const float* __restrict__ wv,
    const char* __restrict__ srcb, int nnz) {
    float a0 = 0.f, a1 = 0.f, a2 = 0.f, a3 = 0.f;
    float a4 = 0.f, a5 = 0.f, a6 = 0.f, a7 = 0.f;
    int j = 0;
    for (; j + 7 < nnz; j += 8) {
        ushort8_t ix = *reinterpret_cast<const ushort8_t*>(&list[j]);      // 1x b128
        float4 w0 = *reinterpret_cast<const float4*>(&wv[j]);              // 1x b128
        float4 w1 = *reinterpret_cast<const float4*>(&wv[j + 4]);          // 1x b128
        a0 += w0.x * *reinterpret_cast<const float*>(srcb + ((size_t)ix[0] << 8));
        a1 += w0.y * *reinterpret_cast<const float*>(srcb + ((size_t)ix[1] << 8));
        a2 += w0.z * *reinterpret_cast<const float*>(srcb + ((size_t)ix[2] << 8));
        a3 += w0.w * *reinterpret_cast<const float*>(srcb + ((size_t)ix[3] << 8));
        a4 += w1.x * *reinterpret_cast<const float*>(srcb + ((size_t)ix[4] << 8));
        a5 += w1.y * *reinterpret_cast<const float*>(srcb + ((size_t)ix[5] << 8));
        a6 += w1.z * *reinterpret_cast<const float*>(srcb + ((size_t)ix[6] << 8));
        a7 += w1.w * *reinterpret_cast<const float*>(srcb + ((size_t)ix[7] << 8));
    }
    for (; j < nnz; ++j)
        a0 += wv[j] * *reinterpret_cast<const float*>(srcb + ((size_t)list[j] << 8));
    return ((a0 + a1) + (a2 + a3)) + ((a4 + a5) + (a6 + a7));
}

// ---------------------------------------------------------------------------
// Row direction: softmax over sources s for each (h,t); h_ts = elu(attn @ hs).
// grid NT, block 256 (wave = head).
// ---------------------------------------------------------------------------
__global__ __launch_bounds__(256) void attn_row_kernel(
    const unsigned long long* __restrict__ mask_row,
    const float* __restrict__ bs, const float* __restrict__ bt,
    const float* __restrict__ hs, float* __restrict__ out_ts) {
    __shared__ __align__(16) unsigned short list[ROW_CAP];
    __shared__ __align__(16) float wbuf[H][ROW_CAP];   // 16 KB
    __shared__ float sums[H];
    __shared__ int wtot[4];

    const int t = blockIdx.x;
    const int tid = threadIdx.x;
    const int nnz = compact_list<NS / 64, ROW_CAP>(
        mask_row, (size_t)t * (NS / 64), list, wtot, tid);
    __syncthreads();

    const int h = tid >> 6, lane = tid & 63;
    const float btv = bt[(size_t)h * NT + t];
    float m = NEGBIG;
    for (int j = lane; j < nnz; j += 64) {
        float p = bs[(size_t)h * NS + list[j]];
        wbuf[h][j] = p;
        m = fmaxf(m, p);
    }
    m = waveMax(m);
    const float mrow = lrelu(btv + m);   // lrelu monotone => exact row max
    float ssum = 0.f;
    for (int j = lane; j < nnz; j += 64) {
        float wv = expf(lrelu(btv + wbuf[h][j]) - mrow);
        wbuf[h][j] = wv;
        ssum += wv;
    }
    ssum = waveSum(ssum);
    if (lane == 0) sums[h] = ssum;
    __syncthreads();

    float rs = sums[h];
    rs = rs > 0.f ? 1.0f / rs : 0.f;
    const char* srcb = (const char*)(hs + (size_t)h * NS * DOUT) + lane * 4;
    float acc = gather_accum(list, wbuf[h], srcb, nnz);
    out_ts[(size_t)t * (H * DOUT) + h * DOUT + lane] = eluf(acc * rs);
}

// ---------------------------------------------------------------------------
// Col direction: softmax over targets t for each (h,s); h_st = elu(attn^T @ ht).
// grid NS, block 256 (wave = head).
// ---------------------------------------------------------------------------
__global__ __launch_bounds__(256) void attn_col_kernel(
    const unsigned long long* __restrict__ mask_col,
    const float* __restrict__ bs, const float* __restrict__ bt,
    const float* __restrict__ ht, float* __restrict__ out_st) {
    __shared__ __align__(16) unsigned short list[COL_CAP];
    __shared__ __align__(16) float wbuf[H][COL_CAP];   // 8 KB
    __shared__ float sums[H];
    __shared__ int wtot[4];

    const int s = blockIdx.x;
    const int tid = threadIdx.x;
    const int nnz = compact_list<NT / 64, COL_CAP>(
        mask_col, (size_t)s * (NT / 64), list, wtot, tid);
    __syncthreads();

    const int h = tid >> 6, lane = tid & 63;
    const float bsv = bs[(size_t)h * NS + s];
    float m = NEGBIG;
    for (int j = lane; j < nnz; j += 64) {
        float p = bt[(size_t)h * NT + list[j]];
        wbuf[h][j] = p;
        m = fmaxf(m, p);
    }
    m = waveMax(m);
    const float mcol = lrelu(bsv + m);
    float ssum = 0.f;
    for (int j = lane; j < nnz; j += 64) {
        float wv = expf(lrelu(bsv + wbuf[h][j]) - mcol);
        wbuf[h][j] = wv;
        ssum += wv;
    }
    ssum = waveSum(ssum);
    if (lane == 0) sums[h] = ssum;
    __syncthreads();

    float rs = sums[h];
    rs = rs > 0.f ? 1.0f / rs : 0.f;
    const char* srcb = (const char*)(ht + (size_t)h * NT * DOUT) + lane * 4;
    float acc = gather_accum(list, wbuf[h], srcb, nnz);
    out_st[(size_t)s * (H * DOUT) + h * DOUT + lane] = eluf(acc * rs);
}

// ---------------------------------------------------------------------------
extern "C" void kernel_launch(void* const* d_in, const int* in_sizes, int n_in,
                              void* d_out, int out_size, void* d_ws, size_t ws_size,
                              hipStream_t stream) {
    const float* input1 = (const float*)d_in[0];  // [8192,128]
    const float* input2 = (const float*)d_in[1];  // [4096,128]
    const float* A      = (const float*)d_in[2];  // [4096,8192]
    const float* Ws     = (const float*)d_in[3];  // [4,128,64]
    const float* Wt     = (const float*)d_in[4];  // [4,128,64]
    const float* a_src  = (const float*)d_in[5];  // [4,64]
    const float* a_tgt  = (const float*)d_in[6];  // [4,64]
    float* out = (float*)d_out;  // out_st [8192,256] then out_ts [4096,256]

    char* ws = (char*)d_ws;
    float* hs = (float*)(ws + 0);                              // 8 MB   [H,NS,64]
    float* ht = (float*)(ws + 8388608);                        // 4 MB   [H,NT,64]
    float* bs = (float*)(ws + 12582912);                       // 128 KB [H,NS]
    float* bt = (float*)(ws + 12713984);                       // 64 KB  [H,NT]
    unsigned long long* mask_row = (unsigned long long*)(ws + 12779520);  // 4 MB
    unsigned long long* mask_col = (unsigned long long*)(ws + 16973824);  // 4 MB

    proj_kernel<<<dim3(NS / 16, H), 256, 0, stream>>>(input1, Ws, a_src, hs, bs, NS);
    proj_kernel<<<dim3(NT / 16, H), 256, 0, stream>>>(input2, Wt, a_tgt, ht, bt, NT);
    mask_kernel<<<dim3(NS / 64, NT / 64), 256, 0, stream>>>(A, mask_row, mask_col);
    attn_row_kernel<<<NT, 256, 0, stream>>>(mask_row, bs, bt, hs,
                                            out + (size_t)NS * (H * DOUT));
    attn_col_kernel<<<NS, 256, 0, stream>>>(mask_col, bs, bt, ht, out);
}